// Round 17
// baseline (177.325 us; speedup 1.0000x reference)
//
#include <hip/hip_runtime.h>
#include <hip/hip_bf16.h>
#include <math.h>

// BoxE scorer:
//   y: (2048, 256) f32 -> boxes: mn = y[:, :128], delta = softplus(y[:, 128:])
//   x: (1024, 128) f32 -> points
//   out[m][n] = -|| per_dim(x[m], box[n]) ||_2, shape (1024, 2048) f32
//
// R16: R15 (ILP-8 dbuf) gave only 63->57us: p4 latency wasn't binding. The
// remaining serializer is the scalar x path — SMEM returns out-of-order so
// every 8-step block waits lgkmcnt(0) on K$-missing s_loads (x thrashes the
// 16KB shared K$). Fix: single-pipe loop. The wave's x-tile (8 rows x 128 k
// = 1024 f32) lives in 16 VGPRs (64 lanes x 16); per k-step, 8 v_readlane
// broadcasts (uniform lane idx k&63) feed the EVALs. No LDS, no SMEM in the
// loop; only the p4 dwordx4 stream, hidden by the named q/r double-buffer
// with x2-unrolled ping-pong (no rename movs).

#define BM 32
#define BN 64
#define TM 8

// ---- prep: y (2048,256) -> p4[k][n] = {center, hd, inv, c2}, [128][2048] ----
__global__ __launch_bounds__(256) void boxe_prep(const float* __restrict__ y,
                                                 float4* __restrict__ p4)
{
    __shared__ float t0[128][9], t1[128][9], t2[128][9], t3[128][9];
    const int tid = threadIdx.x;
    const int n0  = blockIdx.x * 8;

    // phase 1: k-fastest mapping -> coalesced y reads (256B/wave)
#pragma unroll
    for (int i = 0; i < 4; ++i) {
        int j  = i * 256 + tid;        // 0..1023 = 8 n x 128 k
        int k  = j & 127;
        int nl = j >> 7;
        int n  = n0 + nl;
        float mn = y[n * 256 + k];
        float dv = y[n * 256 + 128 + k];
        // stable softplus: max(v,0) + log1p(exp(-|v|))  (matches jax.nn.softplus)
        float delta = fmaxf(dv, 0.0f) + log1pf(expf(-fabsf(dv)));
        float hd  = 0.5f * delta;
        t0[k][nl] = mn + hd;                                // center
        t1[k][nl] = hd;                                     // half-width
        t2[k][nl] = 1.0f / (delta + 1.0f + 1e-10f);         // 1/(dp1+eps)
        t3[k][nl] = hd * (delta - 1.0f / (delta + 1e-10f)); // c2
    }
    __syncthreads();

    // phase 2: n-fastest mapping -> coalesced p4 writes
#pragma unroll
    for (int i = 0; i < 4; ++i) {
        int j  = i * 256 + tid;
        int nl = j & 7;
        int k  = j >> 3;
        p4[k * 2048 + n0 + nl] =
            make_float4(t0[k][nl], t1[k][nl], t2[k][nl], t3[k][nl]);
    }
}

// ---- main: out[m][n] = -sqrt( sum_k per_dim^2 ) ----
// No LDS, no SMEM in loop. Wave: 8 m-rows (x in 16 VGPRs, readlane bcast),
// 64 n (one per lane).
__global__ __launch_bounds__(256, 4) void boxe_main(
    const float4* __restrict__ p4, const float* __restrict__ x,
    float* __restrict__ out)
{
    const int tid  = threadIdx.x;
    const int lane = tid & 63;
    const int wave = __builtin_amdgcn_readfirstlane(tid >> 6);  // uniform
    const int m0   = blockIdx.y * BM + wave * TM;  // this wave's first m-row
    const int n    = blockIdx.x * BN + lane;       // one box per lane

    // Wave x-tile in VGPRs: xXj holds x[(m0+j)*128 + H*64 + lane], H=A(0),B(1).
    const float* xb = x + m0 * 128 + lane;
    float xA0 = xb[0 * 128];      float xB0 = xb[0 * 128 + 64];
    float xA1 = xb[1 * 128];      float xB1 = xb[1 * 128 + 64];
    float xA2 = xb[2 * 128];      float xB2 = xb[2 * 128 + 64];
    float xA3 = xb[3 * 128];      float xB3 = xb[3 * 128 + 64];
    float xA4 = xb[4 * 128];      float xB4 = xb[4 * 128 + 64];
    float xA5 = xb[5 * 128];      float xB5 = xb[5 * 128 + 64];
    float xA6 = xb[6 * 128];      float xB6 = xb[6 * 128 + 64];
    float xA7 = xb[7 * 128];      float xB7 = xb[7 * 128 + 64];

    const float4* pp = p4 + n;

    float acc0 = 0.0f, acc1 = 0.0f, acc2 = 0.0f, acc3 = 0.0f;
    float acc4 = 0.0f, acc5 = 0.0f, acc6 = 0.0f, acc7 = 0.0f;

#define RL(V, LI) __int_as_float(__builtin_amdgcn_readlane(__float_as_int(V), (LI)))

#define EVAL(ACC, SX, P, DP1)                                              \
    do {                                                                   \
        float l = fabsf((SX) - (P).x);                                     \
        float v = (l <= (P).y) ? (l * (P).z) : fmaf(l, (DP1), -(P).w);     \
        ACC = fmaf(v, v, ACC);                                             \
    } while (0)

    // One k-step: row KK, x-half H (A for KK<64, B for KK>=64).
#define STEPX(P, KK, H)                                                    \
    do {                                                                   \
        int li = (KK) & 63;                                                \
        float sx0 = RL(x##H##0, li);                                       \
        float sx1 = RL(x##H##1, li);                                       \
        float sx2 = RL(x##H##2, li);                                       \
        float sx3 = RL(x##H##3, li);                                       \
        float sx4 = RL(x##H##4, li);                                       \
        float sx5 = RL(x##H##5, li);                                       \
        float sx6 = RL(x##H##6, li);                                       \
        float sx7 = RL(x##H##7, li);                                       \
        float dp1 = fmaf(2.0f, (P).y, 1.0f);  /* delta+1, exact */         \
        EVAL(acc0, sx0, P, dp1);                                           \
        EVAL(acc1, sx1, P, dp1);                                           \
        EVAL(acc2, sx2, P, dp1);                                           \
        EVAL(acc3, sx3, P, dp1);                                           \
        EVAL(acc4, sx4, P, dp1);                                           \
        EVAL(acc5, sx5, P, dp1);                                           \
        EVAL(acc6, sx6, P, dp1);                                           \
        EVAL(acc7, sx7, P, dp1);                                           \
    } while (0)

#define LOADR(R0) do {                                                     \
        r0 = pp[((R0) + 0) * 2048]; r1 = pp[((R0) + 1) * 2048];            \
        r2 = pp[((R0) + 2) * 2048]; r3 = pp[((R0) + 3) * 2048];            \
        r4 = pp[((R0) + 4) * 2048]; r5 = pp[((R0) + 5) * 2048];            \
        r6 = pp[((R0) + 6) * 2048]; r7 = pp[((R0) + 7) * 2048];            \
    } while (0)

#define LOADQ(R0) do {                                                     \
        q0 = pp[((R0) + 0) * 2048]; q1 = pp[((R0) + 1) * 2048];            \
        q2 = pp[((R0) + 2) * 2048]; q3 = pp[((R0) + 3) * 2048];            \
        q4 = pp[((R0) + 4) * 2048]; q5 = pp[((R0) + 5) * 2048];            \
        q6 = pp[((R0) + 6) * 2048]; q7 = pp[((R0) + 7) * 2048];            \
    } while (0)

    // Prologue: rows 0..7.
    float4 q0 = pp[0 * 2048], q1 = pp[1 * 2048], q2 = pp[2 * 2048],
           q3 = pp[3 * 2048], q4 = pp[4 * 2048], q5 = pp[5 * 2048],
           q6 = pp[6 * 2048], q7 = pp[7 * 2048];
    float4 r0, r1, r2, r3, r4, r5, r6, r7;

    // First half: rows 0..63 use x-half A. kb = 0,16,32,48.
    for (int kb = 0; kb < 64; kb += 16) {
        LOADR(kb + 8);
        STEPX(q0, kb + 0, A); STEPX(q1, kb + 1, A);
        STEPX(q2, kb + 2, A); STEPX(q3, kb + 3, A);
        STEPX(q4, kb + 4, A); STEPX(q5, kb + 5, A);
        STEPX(q6, kb + 6, A); STEPX(q7, kb + 7, A);
        LOADQ(kb + 16);
        STEPX(r0, kb + 8, A);  STEPX(r1, kb + 9, A);
        STEPX(r2, kb + 10, A); STEPX(r3, kb + 11, A);
        STEPX(r4, kb + 12, A); STEPX(r5, kb + 13, A);
        STEPX(r6, kb + 14, A); STEPX(r7, kb + 15, A);
    }
    // Second half: rows 64..111 use x-half B. kb = 64,80,96.
    for (int kb = 64; kb < 112; kb += 16) {
        LOADR(kb + 8);
        STEPX(q0, kb + 0, B); STEPX(q1, kb + 1, B);
        STEPX(q2, kb + 2, B); STEPX(q3, kb + 3, B);
        STEPX(q4, kb + 4, B); STEPX(q5, kb + 5, B);
        STEPX(q6, kb + 6, B); STEPX(q7, kb + 7, B);
        LOADQ(kb + 16);                      // at kb=96 loads rows 112..119
        STEPX(r0, kb + 8, B);  STEPX(r1, kb + 9, B);
        STEPX(r2, kb + 10, B); STEPX(r3, kb + 11, B);
        STEPX(r4, kb + 12, B); STEPX(r5, kb + 13, B);
        STEPX(r6, kb + 14, B); STEPX(r7, kb + 15, B);
    }
    // Tail: q holds rows 112..119; load 120..127 and finish.
    LOADR(120);
    STEPX(q0, 112, B); STEPX(q1, 113, B); STEPX(q2, 114, B);
    STEPX(q3, 115, B); STEPX(q4, 116, B); STEPX(q5, 117, B);
    STEPX(q6, 118, B); STEPX(q7, 119, B);
    STEPX(r0, 120, B); STEPX(r1, 121, B); STEPX(r2, 122, B);
    STEPX(r3, 123, B); STEPX(r4, 124, B); STEPX(r5, 125, B);
    STEPX(r6, 126, B); STEPX(r7, 127, B);

#undef STEPX
#undef EVAL
#undef RL
#undef LOADR
#undef LOADQ

    out[(m0 + 0) * 2048 + n] = -sqrtf(acc0);
    out[(m0 + 1) * 2048 + n] = -sqrtf(acc1);
    out[(m0 + 2) * 2048 + n] = -sqrtf(acc2);
    out[(m0 + 3) * 2048 + n] = -sqrtf(acc3);
    out[(m0 + 4) * 2048 + n] = -sqrtf(acc4);
    out[(m0 + 5) * 2048 + n] = -sqrtf(acc5);
    out[(m0 + 6) * 2048 + n] = -sqrtf(acc6);
    out[(m0 + 7) * 2048 + n] = -sqrtf(acc7);
}

extern "C" void kernel_launch(void* const* d_in, const int* in_sizes, int n_in,
                              void* d_out, int out_size, void* d_ws, size_t ws_size,
                              hipStream_t stream) {
    const float* y = (const float*)d_in[0];   // 2048*256
    const float* x = (const float*)d_in[1];   // 1024*128
    float* out = (float*)d_out;               // 1024*2048

    float4* p4 = (float4*)d_ws;               // 4 MiB: [128][2048] float4

    hipLaunchKernelGGL(boxe_prep, dim3(2048 / 8), dim3(256), 0, stream, y, p4);

    dim3 grid(2048 / BN, 1024 / BM);          // (32, 32) = 1024 blocks
    hipLaunchKernelGGL(boxe_main, grid, dim3(256), 0, stream, p4, x, out);
}

// Round 18
// 105.477 us; speedup vs baseline: 1.6812x; 1.6812x over previous
//
#include <hip/hip_runtime.h>
#include <hip/hip_bf16.h>
#include <math.h>

// BoxE scorer:
//   y: (2048, 256) f32 -> boxes: mn = y[:, :128], delta = softplus(y[:, 128:])
//   x: (1024, 128) f32 -> points
//   out[m][n] = -|| per_dim(x[m], box[n]) ||_2, shape (1024, 2048) f32
//
// R18: R16 (x-in-VGPR + readlane) spilled q/r (WRITE_SIZE 300MB) — rejected.
// Merge the two proven wins: R15's named q/r register double-buffer (57us,
// VGPR 44, no spill) + R9's 2048-block grid (59% occupancy). TM 8->4 halves
// per-wave register need (q/r 32 + 4 acc + addr ~= 55 <= 64 -> 8 waves/SIMD
// eligible); 2048 blocks double the latency-hiding wave pool. Scalar x path
// (4 uniform rows, s_load). launch_bounds(256,4) — NOT 8 (R9's VGPR squeeze).

#define BM 16
#define BN 64
#define TM 4

// ---- prep: y (2048,256) -> p4[k][n] = {center, hd, inv, c2}, [128][2048] ----
__global__ __launch_bounds__(256) void boxe_prep(const float* __restrict__ y,
                                                 float4* __restrict__ p4)
{
    __shared__ float t0[128][9], t1[128][9], t2[128][9], t3[128][9];
    const int tid = threadIdx.x;
    const int n0  = blockIdx.x * 8;

    // phase 1: k-fastest mapping -> coalesced y reads (256B/wave)
#pragma unroll
    for (int i = 0; i < 4; ++i) {
        int j  = i * 256 + tid;        // 0..1023 = 8 n x 128 k
        int k  = j & 127;
        int nl = j >> 7;
        int n  = n0 + nl;
        float mn = y[n * 256 + k];
        float dv = y[n * 256 + 128 + k];
        // stable softplus: max(v,0) + log1p(exp(-|v|))  (matches jax.nn.softplus)
        float delta = fmaxf(dv, 0.0f) + log1pf(expf(-fabsf(dv)));
        float hd  = 0.5f * delta;
        t0[k][nl] = mn + hd;                                // center
        t1[k][nl] = hd;                                     // half-width
        t2[k][nl] = 1.0f / (delta + 1.0f + 1e-10f);         // 1/(dp1+eps)
        t3[k][nl] = hd * (delta - 1.0f / (delta + 1e-10f)); // c2
    }
    __syncthreads();

    // phase 2: n-fastest mapping -> coalesced p4 writes
#pragma unroll
    for (int i = 0; i < 4; ++i) {
        int j  = i * 256 + tid;
        int nl = j & 7;
        int k  = j >> 3;
        p4[k * 2048 + n0 + nl] =
            make_float4(t0[k][nl], t1[k][nl], t2[k][nl], t3[k][nl]);
    }
}

// ---- main: out[m][n] = -sqrt( sum_k per_dim^2 ) ----
// No LDS. Wave: 4 m-rows (x scalar path), 64 n (one per lane).
__global__ __launch_bounds__(256, 4) void boxe_main(
    const float4* __restrict__ p4, const float* __restrict__ x,
    float* __restrict__ out)
{
    const int tid  = threadIdx.x;
    const int lane = tid & 63;
    const int wave = __builtin_amdgcn_readfirstlane(tid >> 6);  // uniform
    const int m0   = blockIdx.y * BM + wave * TM;  // this wave's first m-row
    const int n    = blockIdx.x * BN + lane;       // one box per lane

    // Uniform row pointers -> x reads are scalar (s_load) from K$.
    const float* xr0 = x + (m0 + 0) * 128;
    const float* xr1 = x + (m0 + 1) * 128;
    const float* xr2 = x + (m0 + 2) * 128;
    const float* xr3 = x + (m0 + 3) * 128;

    const float4* pp = p4 + n;

    float acc0 = 0.0f, acc1 = 0.0f, acc2 = 0.0f, acc3 = 0.0f;

    // One k-step: consume params P at k-row KK against the wave's 4 x-values.
#define STEP(P, KK)                                                        \
    do {                                                                   \
        float dp1 = fmaf(2.0f, (P).y, 1.0f);  /* delta+1, exact */         \
        float l0 = fabsf(xr0[(KK)] - (P).x);                               \
        float l1 = fabsf(xr1[(KK)] - (P).x);                               \
        float l2 = fabsf(xr2[(KK)] - (P).x);                               \
        float l3 = fabsf(xr3[(KK)] - (P).x);                               \
        float v0 = (l0 <= (P).y) ? (l0 * (P).z) : fmaf(l0, dp1, -(P).w);   \
        float v1 = (l1 <= (P).y) ? (l1 * (P).z) : fmaf(l1, dp1, -(P).w);   \
        float v2 = (l2 <= (P).y) ? (l2 * (P).z) : fmaf(l2, dp1, -(P).w);   \
        float v3 = (l3 <= (P).y) ? (l3 * (P).z) : fmaf(l3, dp1, -(P).w);   \
        acc0 = fmaf(v0, v0, acc0);                                         \
        acc1 = fmaf(v1, v1, acc1);                                         \
        acc2 = fmaf(v2, v2, acc2);                                         \
        acc3 = fmaf(v3, v3, acc3);                                         \
    } while (0)

    // Prologue: rows 0..7 live in named registers.
    float4 q0 = pp[0 * 2048];
    float4 q1 = pp[1 * 2048];
    float4 q2 = pp[2 * 2048];
    float4 q3 = pp[3 * 2048];
    float4 q4 = pp[4 * 2048];
    float4 q5 = pp[5 * 2048];
    float4 q6 = pp[6 * 2048];
    float4 q7 = pp[7 * 2048];

    // Steady state: prefetch next 8 rows, compute current 8, rename.
    int kb = 0;
    for (int it = 0; it < 15; ++it, kb += 8) {
        float4 r0 = pp[(kb +  8) * 2048];
        float4 r1 = pp[(kb +  9) * 2048];
        float4 r2 = pp[(kb + 10) * 2048];
        float4 r3 = pp[(kb + 11) * 2048];
        float4 r4 = pp[(kb + 12) * 2048];
        float4 r5 = pp[(kb + 13) * 2048];
        float4 r6 = pp[(kb + 14) * 2048];
        float4 r7 = pp[(kb + 15) * 2048];
        STEP(q0, kb + 0);
        STEP(q1, kb + 1);
        STEP(q2, kb + 2);
        STEP(q3, kb + 3);
        STEP(q4, kb + 4);
        STEP(q5, kb + 5);
        STEP(q6, kb + 6);
        STEP(q7, kb + 7);
        q0 = r0; q1 = r1; q2 = r2; q3 = r3;
        q4 = r4; q5 = r5; q6 = r6; q7 = r7;
    }
    // Epilogue: rows 120..127.
    STEP(q0, 120); STEP(q1, 121); STEP(q2, 122); STEP(q3, 123);
    STEP(q4, 124); STEP(q5, 125); STEP(q6, 126); STEP(q7, 127);
#undef STEP

    out[(m0 + 0) * 2048 + n] = -sqrtf(acc0);
    out[(m0 + 1) * 2048 + n] = -sqrtf(acc1);
    out[(m0 + 2) * 2048 + n] = -sqrtf(acc2);
    out[(m0 + 3) * 2048 + n] = -sqrtf(acc3);
}

extern "C" void kernel_launch(void* const* d_in, const int* in_sizes, int n_in,
                              void* d_out, int out_size, void* d_ws, size_t ws_size,
                              hipStream_t stream) {
    const float* y = (const float*)d_in[0];   // 2048*256
    const float* x = (const float*)d_in[1];   // 1024*128
    float* out = (float*)d_out;               // 1024*2048

    float4* p4 = (float4*)d_ws;               // 4 MiB: [128][2048] float4

    hipLaunchKernelGGL(boxe_prep, dim3(2048 / 8), dim3(256), 0, stream, y, p4);

    dim3 grid(2048 / BN, 1024 / BM);          // (32, 64) = 2048 blocks
    hipLaunchKernelGGL(boxe_main, grid, dim3(256), 0, stream, p4, x, out);
}